// Round 8
// baseline (2315.556 us; speedup 1.0000x reference)
//
#include <hip/hip_runtime.h>
#include <hip/hip_bf16.h>

// TTCN: h=relu(X@W1+b1); h=relu(h@W2+b2); filt=h@W3+b3; masked softmax over Lx;
// out[n,k]=relu(sum_{l,d} X[n,l,d]*softmax(filt)[n,l,k,d] + T_bias[k])
// N=128, LX=512, D=32, K=63, C=2016.
// R8: ONE persistent kernel (1024 blocks, all co-resident by __launch_bounds__
// (256,4): 256 CU x 4 blocks). Phase A (producer): per-block mask scan, inline
// weight-frag gather, bf16-MFMA MLP, compacted Hc/Xt stores, pad zeroing,
// W3fr slab packing; then threadfence + release MAGIC flags (agent scope).
// Phase B (consumer): block b handles att tiles {b, b+1024, b+2048} (all the
// same n = b&127 -> one XCD's L2 holds that n's 128 KB), acquire-spins on the
// 8 producer slots of n and the 24 W3fr slab slots of each bt, then fused
// logits-MFMA + exp2 + pooling. Mask compaction: masked rows contribute
// exactly 0; pad rows have H==0 -> e==exp2(0)==1.0 exactly -> s accumulated
// unconditionally, scalar pad count subtracted at the end. Biases ride the
// MFMA K-dim: h1[63]=1 & W2 row63=b2 => H[:,63]=1; W3fr row63=b3*log2e
// (W3 prescaled by log2e -> raw v_exp_f32).

#define N_   128
#define LX_  512
#define D_   32
#define K_   63
#define C_   2016
#define LOG2E 1.44269504088896f
#define MAGIC 0x5A5A5A5Au

typedef __bf16 bf16x8 __attribute__((ext_vector_type(8)));
typedef float floatx4 __attribute__((ext_vector_type(4)));
typedef float floatx2 __attribute__((ext_vector_type(2)));

static __device__ __forceinline__ floatx4 mfma16(bf16x8 a, bf16x8 b, floatx4 c) {
  return __builtin_amdgcn_mfma_f32_16x16x32_bf16(a, b, c, 0, 0, 0);
}

// ws layout (bytes)
#define HC_OFF   0u                        // 128n x 512row x 64 bf16 = 8 MiB (compacted)
#define XT_OFF   (8u * 1024u * 1024u)      // 128n x 32chunk x 32d x 16row f32 = 8 MiB
#define W3FR_OFF (16u * 1024u * 1024u)     // 129024 bf16 frag-packed (*log2e, row63=b3)
#define CNT_OFF  (W3FR_OFF + 258048u)      // 128 i32
#define RS_OFF   (CNT_OFF + 512u)          // 1024 u32: per-(n,blk8) ready slots
#define W3S_OFF  (RS_OFF + 4096u)          // 504 u32: per-W3fr-slab ready slots

__global__ __launch_bounds__(256, 4) void kern_fused(
    const float* __restrict__ X, const float* __restrict__ Mk,
    const float* __restrict__ W1, const float* __restrict__ b1,
    const float* __restrict__ W2, const float* __restrict__ b2,
    const float* __restrict__ W3, const float* __restrict__ b3,
    const float* __restrict__ Tb, float* __restrict__ out,
    __bf16* __restrict__ Hc, float* __restrict__ Xt,
    __bf16* __restrict__ W3fr, int* __restrict__ cnt,
    unsigned* __restrict__ rs, unsigned* __restrict__ w3s) {
  __shared__ int pos_s[64];
  __shared__ int s_cnt;
  __shared__ float h1s[4][16][68];   // per-wave transpose tile
  __shared__ float redS[4][96], redO[4][96];
  __shared__ float rbuf[96];

  const int tid = threadIdx.x;
  const int w = tid >> 6, lane = tid & 63, quad = lane >> 4, l16 = lane & 15;
  const int b = blockIdx.x;
  const int n = b >> 3, blk8 = b & 7;

  // ================= Phase A: producer =================
  // ---- wave 0: mask prefix scan for this n (stores only our 64 rows) ----
  if (tid < 64) {
    int running = 0;
#pragma unroll
    for (int c = 0; c < 8; ++c) {
      const float mkv = Mk[n * LX_ + c * 64 + tid];
      const unsigned long long bl = __ballot(mkv > 0.5f);
      const int mypos = running + __popcll(bl & ((1ull << tid) - 1ull));
      if (c == blk8) pos_s[tid] = (mkv > 0.5f) ? mypos : -1;
      running += __popcll(bl);
    }
    if (tid == 0) {
      s_cnt = running;
      if (blk8 == 0) cnt[n] = running;
    }
  }

  // ---- inline weight-fragment gather (W1/W2/b1/b2 tiny, L1/L2-hot) ----
  bf16x8 b1f[4], b2f[4][2];
  float b1v[4];
#pragma unroll
  for (int i = 0; i < 4; ++i) {
    const int ch = i * 16 + l16;
    const int chc = (ch < K_) ? ch : 62;
#pragma unroll
    for (int j = 0; j < 8; ++j) {
      const int t = quad * 8 + j;                   // 0..31
      b1f[i][j] = (__bf16)((ch < K_) ? W1[t * K_ + chc] : 0.f);
    }
    b1v[i] = (ch < K_) ? b1[chc] : 0.f;
    const float b2c = (ch < K_) ? b2[chc] : 0.f;
#pragma unroll
    for (int h = 0; h < 2; ++h) {
#pragma unroll
      for (int j = 0; j < 8; ++j) {
        const int t = h * 32 + quad * 8 + j;        // 0..63
        const float w2v = W2[((t < K_) ? t : 62) * K_ + chc];
        float v;
        if (ch < K_) v = (t < K_) ? w2v : b2c;      // row63 = b2
        else         v = (t < K_) ? 0.f : 1.f;      // [63][63]=1 keeps H[:,63]=1
        b2f[i][h][j] = (__bf16)v;
      }
    }
  }

  const int tok0 = b * 64 + w * 16;
  const float* xp = X + (size_t)(tok0 + l16) * D_ + quad * 8;
  const float4 xa = *(const float4*)xp;
  const float4 xb = *(const float4*)(xp + 4);
  bf16x8 a1;
  a1[0]=(__bf16)xa.x; a1[1]=(__bf16)xa.y; a1[2]=(__bf16)xa.z; a1[3]=(__bf16)xa.w;
  a1[4]=(__bf16)xb.x; a1[5]=(__bf16)xb.y; a1[6]=(__bf16)xb.z; a1[7]=(__bf16)xb.w;

  __syncthreads();                                  // pos_s/s_cnt ready

  const int px = pos_s[w * 16 + l16];
  const int4 pr4 = *(const int4*)&pos_s[w * 16 + quad * 4];

  if (px >= 0) {  // compacted X f32 d-planes (mask==1 here, so X*mask == X)
    float* xtp = Xt + ((size_t)(n * 32 + (px >> 4)) * 32 + quad * 8) * 16 + (px & 15);
    const float vals[8] = {xa.x, xa.y, xa.z, xa.w, xb.x, xb.y, xb.z, xb.w};
#pragma unroll
    for (int j = 0; j < 8; ++j) xtp[j * 16] = vals[j];
  }

#pragma unroll
  for (int i = 0; i < 4; ++i) {
    floatx4 acc = {0.f, 0.f, 0.f, 0.f};
    acc = mfma16(a1, b1f[i], acc);
#pragma unroll
    for (int r = 0; r < 4; ++r) {
      float v = fmaxf(acc[r] + b1v[i], 0.f);
      if (i == 3 && l16 == 15) v = 1.f;   // h1 col63 := 1 (layer-2 bias row)
      h1s[w][quad * 4 + r][i * 16 + l16] = v;
    }
  }
  // no barrier: h1s[w] produced and consumed by the same wave (lgkmcnt orders)

  const float* hrow = &h1s[w][l16][0];
  const float4 p0 = *(const float4*)(hrow + quad * 8);
  const float4 p1 = *(const float4*)(hrow + quad * 8 + 4);
  const float4 p2 = *(const float4*)(hrow + 32 + quad * 8);
  const float4 p3 = *(const float4*)(hrow + 32 + quad * 8 + 4);
  bf16x8 a20, a21;
  a20[0]=(__bf16)p0.x; a20[1]=(__bf16)p0.y; a20[2]=(__bf16)p0.z; a20[3]=(__bf16)p0.w;
  a20[4]=(__bf16)p1.x; a20[5]=(__bf16)p1.y; a20[6]=(__bf16)p1.z; a20[7]=(__bf16)p1.w;
  a21[0]=(__bf16)p2.x; a21[1]=(__bf16)p2.y; a21[2]=(__bf16)p2.z; a21[3]=(__bf16)p2.w;
  a21[4]=(__bf16)p3.x; a21[5]=(__bf16)p3.y; a21[6]=(__bf16)p3.z; a21[7]=(__bf16)p3.w;

  const int pr[4] = {pr4.x, pr4.y, pr4.z, pr4.w};
#pragma unroll
  for (int i = 0; i < 4; ++i) {
    floatx4 acc = {0.f, 0.f, 0.f, 0.f};
    acc = mfma16(a20, b2f[i][0], acc);
    acc = mfma16(a21, b2f[i][1], acc);  // bias via k=63 (h1 col63 == 1)
#pragma unroll
    for (int r = 0; r < 4; ++r) {
      if (pr[r] >= 0)
        Hc[((size_t)(n * 512 + pr[r])) * 64 + i * 16 + l16] =
            (__bf16)fmaxf(acc[r], 0.f);
    }
  }

  // ---- pad zeroing of the last 16-granule (<=15 rows), one block per n ----
  if (blk8 == 7) {
    const int c0 = s_cnt, c1 = (c0 + 15) & ~15;
    const float4 z = {0.f, 0.f, 0.f, 0.f};
    for (int idx2 = tid; idx2 < (c1 - c0) * 40; idx2 += 256) {
      const int row = c0 + idx2 / 40, q = idx2 % 40;
      if (q < 8) *(float4*)(Hc + ((size_t)(n * 512 + row)) * 64 + q * 8) = z;
      else Xt[((size_t)(n * 32 + (row >> 4)) * 32 + (q - 8)) * 16 + (row & 15)] = 0.f;
    }
  }

  // ---- W3fr slab pack: blocks 0..503, 256 elems each ----
  if (b < 504) {   // [tile21][i6][h2][l16][quad][8], *log2e, row63=b3*log2e
    const int g = b * 256 + tid;
    const int j2 = g & 7, q2 = (g >> 3) & 3, l2 = (g >> 5) & 15, h2 = (g >> 9) & 1;
    const int rest = g >> 10, i2 = rest % 6, tile = rest / 6;
    const int c = tile * 96 + i2 * 16 + l2;
    const int t = h2 * 32 + q2 * 8 + j2;
    W3fr[g] = (__bf16)(((t < K_) ? W3[(size_t)t * C_ + c] : b3[c]) * LOG2E);
  }

  // ---- publish: fence all stores, then release MAGIC flags ----
  __threadfence();
  __syncthreads();
  if (tid == 0) {
    __hip_atomic_store(&rs[n * 8 + blk8], MAGIC, __ATOMIC_RELEASE,
                       __HIP_MEMORY_SCOPE_AGENT);
    if (b < 504)
      __hip_atomic_store(&w3s[b], MAGIC, __ATOMIC_RELEASE,
                         __HIP_MEMORY_SCOPE_AGENT);
  }

  // ================= Phase B: consumer =================
  const int nc = b & 127;   // all 3 tiles share this n; b%8==nc%8 -> same XCD
  // wait for all 8 producer blocks of nc (all threads spin: each gets acquire)
#pragma unroll 1
  for (int j = 0; j < 8; ++j)
    while (__hip_atomic_load(&rs[nc * 8 + j], __ATOMIC_ACQUIRE,
                             __HIP_MEMORY_SCOPE_AGENT) != MAGIC)
      __builtin_amdgcn_s_sleep(2);

  const int cntn = cnt[nc];
  const int nch = (cntn + 15) >> 4;                 // 16-row chunks (typ. 14..19)
  const __bf16* Hb = Hc + ((size_t)nc << 9) * 64 + l16 * 64 + quad * 8;
  const float*  Xb = Xt + (size_t)nc * 16384 + l16 * 16 + quad * 4;

#pragma unroll 1
  for (int u = 0; u < 3; ++u) {
    const int a = b + u * 1024;
    if (a >= 2688) break;
    const int bt = a >> 7;

    // wait for the 24 W3fr slabs of tile bt
#pragma unroll 1
    for (int j = 0; j < 24; ++j)
      while (__hip_atomic_load(&w3s[bt * 24 + j], __ATOMIC_ACQUIRE,
                               __HIP_MEMORY_SCOPE_AGENT) != MAGIC)
        __builtin_amdgcn_s_sleep(2);

    bf16x8 bf[6][2];
#pragma unroll
    for (int i = 0; i < 6; ++i) {
      bf[i][0] = *(const bf16x8*)(W3fr + ((((bt * 6 + i) * 2 + 0) * 16 + l16) * 4 + quad) * 8);
      bf[i][1] = *(const bf16x8*)(W3fr + ((((bt * 6 + i) * 2 + 1) * 16 + l16) * 4 + quad) * 8);
    }

    floatx2 s2[3] = {{0.f, 0.f}, {0.f, 0.f}, {0.f, 0.f}};
    floatx2 o2[3] = {{0.f, 0.f}, {0.f, 0.f}, {0.f, 0.f}};

    int c = w;
    bf16x8 a0 = *(const bf16x8*)(Hb + (size_t)c * 1024);
    bf16x8 a1c = *(const bf16x8*)(Hb + (size_t)c * 1024 + 32);
    float4 xl4 = *(const float4*)(Xb + c * 512);
    float4 xh4 = *(const float4*)(Xb + c * 512 + 256);

#pragma unroll 1
    while (c < nch) {
      const int cn = c + 4;
      bf16x8 na0, na1;
      float4 nxl, nxh;
      if (cn < nch) {                               // wave-uniform prefetch
        na0 = *(const bf16x8*)(Hb + (size_t)cn * 1024);
        na1 = *(const bf16x8*)(Hb + (size_t)cn * 1024 + 32);
        nxl = *(const float4*)(Xb + cn * 512);
        nxh = *(const float4*)(Xb + cn * 512 + 256);
      }
#pragma unroll
      for (int t = 0; t < 3; ++t) {
        floatx4 accE = {0.f, 0.f, 0.f, 0.f};
        floatx4 accO = {0.f, 0.f, 0.f, 0.f};
        accE = mfma16(a0, bf[2 * t][0], accE);
        accE = mfma16(a1c, bf[2 * t][1], accE);     // logit*log2e incl. b3
        accO = mfma16(a0, bf[2 * t + 1][0], accO);
        accO = mfma16(a1c, bf[2 * t + 1][1], accO);
#pragma unroll
        for (int r = 0; r < 4; ++r) {
          floatx2 e2, x2;
          e2.x = __builtin_amdgcn_exp2f(accE[r]);
          e2.y = __builtin_amdgcn_exp2f(accO[r]);
          x2.x = xl4[r];
          x2.y = xh4[r];
          s2[t] += e2;                              // pad rows add exactly 1.0
          o2[t] += e2 * x2;                         // pk_fma; x==0 on pad rows
        }
      }
      c = cn;
      a0 = na0; a1c = na1; xl4 = nxl; xh4 = nxh;    // garbage on exit: unused
    }

    // reduce the 4 quads (row groups) within each wave
#pragma unroll
    for (int t = 0; t < 3; ++t) {
      s2[t].x += __shfl_xor(s2[t].x, 16); s2[t].x += __shfl_xor(s2[t].x, 32);
      s2[t].y += __shfl_xor(s2[t].y, 16); s2[t].y += __shfl_xor(s2[t].y, 32);
      o2[t].x += __shfl_xor(o2[t].x, 16); o2[t].x += __shfl_xor(o2[t].x, 32);
      o2[t].y += __shfl_xor(o2[t].y, 16); o2[t].y += __shfl_xor(o2[t].y, 32);
    }
    __syncthreads();                                // redS/redO/rbuf reuse (WAR)
    if (quad == 0) {
#pragma unroll
      for (int t = 0; t < 3; ++t) {
        redS[w][(2 * t) * 16 + l16]     = s2[t].x;
        redS[w][(2 * t + 1) * 16 + l16] = s2[t].y;
        redO[w][(2 * t) * 16 + l16]     = o2[t].x;
        redO[w][(2 * t + 1) * 16 + l16] = o2[t].y;
      }
    }
    __syncthreads();
    if (tid < 96) {
      const float pad = (float)(nch * 16 - cntn);   // exact pad contribution to S
      const float S = redS[0][tid] + redS[1][tid] + redS[2][tid] + redS[3][tid] - pad;
      const float O = redO[0][tid] + redO[1][tid] + redO[2][tid] + redO[3][tid];
      rbuf[tid] = O / S;
    }
    __syncthreads();
    if (tid < 3) {
      float acc = 0.f;
#pragma unroll
      for (int dd = 0; dd < 32; ++dd) acc += rbuf[tid * 32 + dd];
      const int k = bt * 3 + tid;
      out[nc * K_ + k] = fmaxf(acc + Tb[k], 0.f);
    }
  }
}

extern "C" void kernel_launch(void* const* d_in, const int* in_sizes, int n_in,
                              void* d_out, int out_size, void* d_ws, size_t ws_size,
                              hipStream_t stream) {
  const float* X  = (const float*)d_in[0];
  const float* Mk = (const float*)d_in[1];
  const float* W1 = (const float*)d_in[2];
  const float* b1 = (const float*)d_in[3];
  const float* W2 = (const float*)d_in[4];
  const float* b2 = (const float*)d_in[5];
  const float* W3 = (const float*)d_in[6];
  const float* b3 = (const float*)d_in[7];
  const float* Tb = (const float*)d_in[8];
  float* out = (float*)d_out;

  char* ws = (char*)d_ws;
  __bf16*   Hc   = (__bf16*)(ws + HC_OFF);
  float*    Xt   = (float*)(ws + XT_OFF);
  __bf16*   W3fr = (__bf16*)(ws + W3FR_OFF);
  int*      cnt  = (int*)(ws + CNT_OFF);
  unsigned* rs   = (unsigned*)(ws + RS_OFF);
  unsigned* w3s  = (unsigned*)(ws + W3S_OFF);

  kern_fused<<<1024, 256, 0, stream>>>(X, Mk, W1, b1, W2, b2, W3, b3, Tb, out,
                                       Hc, Xt, W3fr, cnt, rs, w3s);
}

// Round 9
// 112.762 us; speedup vs baseline: 20.5349x; 20.5349x over previous
//
#include <hip/hip_runtime.h>
#include <hip/hip_bf16.h>

// TTCN: h=relu(X@W1+b1); h=relu(h@W2+b2); filt=h@W3+b3; masked softmax over Lx;
// out[n,k]=relu(sum_{l,d} X[n,l,d]*softmax(filt)[n,l,k,d] + T_bias[k])
// N=128, LX=512, D=32, K=63, C=2016.
// R9 = revert to R5 (measured optimum, 112.89 us).
// Mask compaction (masked rows contribute exactly 0) + pad-count trick:
// pad rows have H==0 -> logit==0 -> e==exp2(0)==1.0 exactly, so s accumulates
// unconditionally (v_pk_add_f32 pairs) and the scalar pad count is subtracted
// at the end. X is pre-transposed to f32 d-planes so the epilogue x-loads are
// 2 coalesced b128/wave. 16-row chunks round-robin over waves (tail waste ~5%).
// Biases ride the MFMA K-dim: h1[63]=1 & W2 row63=b2 => H[:,63]=1;
// W3fr row63 = b3*log2e (whole W3 prescaled by log2e -> raw v_exp_f32).

#define N_   128
#define LX_  512
#define D_   32
#define K_   63
#define C_   2016
#define LOG2E 1.44269504088896f

typedef __bf16 bf16x8 __attribute__((ext_vector_type(8)));
typedef float floatx4 __attribute__((ext_vector_type(4)));
typedef float floatx2 __attribute__((ext_vector_type(2)));

static __device__ __forceinline__ floatx4 mfma16(bf16x8 a, bf16x8 b, floatx4 c) {
  return __builtin_amdgcn_mfma_f32_16x16x32_bf16(a, b, c, 0, 0, 0);
}

// ws layout (bytes)
#define HC_OFF   0u                        // 128n x 512row x 64 bf16 = 8 MiB (compacted)
#define XT_OFF   (8u * 1024u * 1024u)      // 128n x 32chunk x 32d x 16row f32 = 8 MiB
#define W3FR_OFF (16u * 1024u * 1024u)     // 129024 bf16 frag-packed, *log2e, row63=b3*log2e
#define W1FR_OFF (W3FR_OFF + 258048u)      // 2048 bf16
#define W2FR_OFF (W1FR_OFF + 4096u)        // 4096 bf16
#define B1_OFF   (W2FR_OFF + 8192u)        // 64 f32
#define POS_OFF  (B1_OFF + 256u)           // 65536 i32
#define CNT_OFF  (POS_OFF + 262144u)       // 128 i32

// ---------------- P: mask scan + pad-zeroing + weight frag packing -----------
__global__ __launch_bounds__(256) void kern_prep(
    const float* __restrict__ Mk,
    const float* __restrict__ W1, const float* __restrict__ b1,
    const float* __restrict__ W2, const float* __restrict__ b2,
    const float* __restrict__ W3, const float* __restrict__ b3,
    __bf16* __restrict__ W3fr, __bf16* __restrict__ W1fr,
    __bf16* __restrict__ W2fr, float* __restrict__ b1pad,
    int* __restrict__ pos, int* __restrict__ cnt,
    __bf16* __restrict__ Hc, float* __restrict__ Xt) {
  const int n = blockIdx.x, tid = threadIdx.x;
  __shared__ int s_cnt;

  if (tid < 64) {                       // wave 0: exclusive scan of the mask
    const int lane = tid;
    int running = 0;
#pragma unroll
    for (int c = 0; c < 8; ++c) {
      const int l = c * 64 + lane;
      const float mkv = Mk[n * LX_ + l];
      const unsigned long long b = __ballot(mkv > 0.5f);
      const int mypos = running + __popcll(b & ((1ull << lane) - 1ull));
      pos[n * LX_ + l] = (mkv > 0.5f) ? mypos : -1;
      running += __popcll(b);
    }
    if (lane == 0) { cnt[n] = running; s_cnt = running; }
  }
  __syncthreads();

  // zero padding rows [cnt, ceil64(cnt)): Hc (8 float4/row) + Xt (32 dword/row)
  const int c0 = s_cnt, c1 = (c0 + 63) & ~63;
  const float4 z = {0.f, 0.f, 0.f, 0.f};
  for (int idx = tid; idx < (c1 - c0) * 40; idx += 256) {
    const int row = c0 + idx / 40, q = idx % 40;
    if (q < 8) {
      *(float4*)(Hc + ((size_t)(n * 512 + row)) * 64 + q * 8) = z;
    } else {
      const int d = q - 8;
      Xt[((size_t)(n * 32 + (row >> 4)) * 32 + d) * 16 + (row & 15)] = 0.f;
    }
  }

  // weight packing (grid-stride over all slots)
  for (int g = n * 256 + tid; g < 129024 + 2048 + 4096 + 64; g += N_ * 256) {
    if (g < 129024) {                     // W3fr: [tile21][i6][h2][l16][quad][8], *log2e
      const int j = g & 7, quad = (g >> 3) & 3, l16 = (g >> 5) & 15, h = (g >> 9) & 1;
      const int rest = g >> 10, i = rest % 6, tile = rest / 6;
      const int c = tile * 96 + i * 16 + l16;
      const int t = h * 32 + quad * 8 + j;
      W3fr[g] = (__bf16)(((t < K_) ? W3[(size_t)t * C_ + c] : b3[c]) * LOG2E);
    } else if (g < 129024 + 2048) {       // W1fr: [i4][l16][quad][8]
      const int g2 = g - 129024;
      const int j = g2 & 7, quad = (g2 >> 3) & 3, l16 = (g2 >> 5) & 15, i = g2 >> 9;
      const int ch = i * 16 + l16, t = quad * 8 + j;
      W1fr[g2] = (__bf16)((ch < K_) ? W1[t * K_ + ch] : 0.f);
    } else if (g < 129024 + 2048 + 4096) {// W2fr: [i4][h2][l16][quad][8], row63=b2, [63][63]=1
      const int g2 = g - 129024 - 2048;
      const int j = g2 & 7, quad = (g2 >> 3) & 3, l16 = (g2 >> 5) & 15, h = (g2 >> 9) & 1;
      const int i = g2 >> 10;
      const int ch = i * 16 + l16, t = h * 32 + quad * 8 + j;
      float v;
      if (t < K_) v = (ch < K_) ? W2[t * K_ + ch] : 0.f;
      else        v = (ch < K_) ? b2[ch] : 1.f;
      W2fr[g2] = (__bf16)v;
    } else {
      const int g2 = g - 129024 - 2048 - 4096;
      b1pad[g2] = (g2 < K_) ? b1[g2] : 0.f;
    }
  }
}

// ---------------- M: Hc(bf16, compacted) = MLP(X); Xt = compacted X planes ---
// One 16-token tile per wave; barrier-free (per-wave LDS transpose only).
__global__ __launch_bounds__(256) void kern_mlp(
    const float* __restrict__ X, const __bf16* __restrict__ W1fr,
    const __bf16* __restrict__ W2fr, const float* __restrict__ b1pad,
    const int* __restrict__ pos, __bf16* __restrict__ Hc,
    float* __restrict__ Xt) {
  __shared__ float h1s[4][16][68];   // per-wave transpose tile
  const int tid = threadIdx.x;
  const int w = tid >> 6, lane = tid & 63, quad = lane >> 4, l16 = lane & 15;

  bf16x8 b1f[4], b2f[4][2];
  float b1v[4];
#pragma unroll
  for (int i = 0; i < 4; ++i) {
    b1f[i]    = *(const bf16x8*)(W1fr + ((i * 16 + l16) * 4 + quad) * 8);
    b2f[i][0] = *(const bf16x8*)(W2fr + (((i * 2 + 0) * 16 + l16) * 4 + quad) * 8);
    b2f[i][1] = *(const bf16x8*)(W2fr + (((i * 2 + 1) * 16 + l16) * 4 + quad) * 8);
    b1v[i] = b1pad[i * 16 + l16];
  }

  const int tok0 = blockIdx.x * 64 + w * 16;
  const int n = tok0 >> 9;
  const float* xp = X + (size_t)(tok0 + l16) * D_ + quad * 8;
  const float4 xa = *(const float4*)xp;
  const float4 xb = *(const float4*)(xp + 4);
  bf16x8 a1;
  a1[0]=(__bf16)xa.x; a1[1]=(__bf16)xa.y; a1[2]=(__bf16)xa.z; a1[3]=(__bf16)xa.w;
  a1[4]=(__bf16)xb.x; a1[5]=(__bf16)xb.y; a1[6]=(__bf16)xb.z; a1[7]=(__bf16)xb.w;

  // compaction indirection
  const int px = pos[tok0 + l16];
  int pr[4];
#pragma unroll
  for (int r = 0; r < 4; ++r) pr[r] = pos[tok0 + quad * 4 + r];

  if (px >= 0) {  // compacted X f32 d-planes (mask==1 here, so X*mask == X)
    float* xtp = Xt + ((size_t)(n * 32 + (px >> 4)) * 32 + quad * 8) * 16 + (px & 15);
    const float vals[8] = {xa.x, xa.y, xa.z, xa.w, xb.x, xb.y, xb.z, xb.w};
#pragma unroll
    for (int j = 0; j < 8; ++j) xtp[j * 16] = vals[j];
  }

#pragma unroll
  for (int i = 0; i < 4; ++i) {
    floatx4 acc = {0.f, 0.f, 0.f, 0.f};
    acc = mfma16(a1, b1f[i], acc);
#pragma unroll
    for (int r = 0; r < 4; ++r) {
      float v = fmaxf(acc[r] + b1v[i], 0.f);
      if (i == 3 && l16 == 15) v = 1.f;   // h1 col63 := 1 (layer-2 bias row)
      h1s[w][quad * 4 + r][i * 16 + l16] = v;
    }
  }
  // no barrier: h1s[w] is produced and consumed by the same wave (lgkmcnt orders)

  const float* hrow = &h1s[w][l16][0];
  const float4 p0 = *(const float4*)(hrow + quad * 8);
  const float4 p1 = *(const float4*)(hrow + quad * 8 + 4);
  const float4 p2 = *(const float4*)(hrow + 32 + quad * 8);
  const float4 p3 = *(const float4*)(hrow + 32 + quad * 8 + 4);
  bf16x8 a20, a21;
  a20[0]=(__bf16)p0.x; a20[1]=(__bf16)p0.y; a20[2]=(__bf16)p0.z; a20[3]=(__bf16)p0.w;
  a20[4]=(__bf16)p1.x; a20[5]=(__bf16)p1.y; a20[6]=(__bf16)p1.z; a20[7]=(__bf16)p1.w;
  a21[0]=(__bf16)p2.x; a21[1]=(__bf16)p2.y; a21[2]=(__bf16)p2.z; a21[3]=(__bf16)p2.w;
  a21[4]=(__bf16)p3.x; a21[5]=(__bf16)p3.y; a21[6]=(__bf16)p3.z; a21[7]=(__bf16)p3.w;

#pragma unroll
  for (int i = 0; i < 4; ++i) {
    floatx4 acc = {0.f, 0.f, 0.f, 0.f};
    acc = mfma16(a20, b2f[i][0], acc);
    acc = mfma16(a21, b2f[i][1], acc);  // bias via k=63 (h1 col63 == 1)
#pragma unroll
    for (int r = 0; r < 4; ++r) {
      if (pr[r] >= 0)
        Hc[((size_t)(n * 512 + pr[r])) * 64 + i * 16 + l16] =
            (__bf16)fmaxf(acc[r], 0.f);
    }
  }
}

// ---------------- A: fused logits-MFMA + exp2 + pooling (compacted rows) -----
// Block = (n, 96-ch tile). 16-row chunks round-robin over waves (c = w; c += 4),
// software-pipelined 1 chunk deep. s accumulated unconditionally (pk_add pairs);
// pad rows contribute exactly 1.0 each, subtracted as a scalar at the end.
__global__ __launch_bounds__(256) void kern_att(
    const __bf16* __restrict__ Hc, const float* __restrict__ Xt,
    const __bf16* __restrict__ W3fr, const int* __restrict__ cnt,
    const float* __restrict__ Tb, float* __restrict__ out) {
  __shared__ float redS[4][96], redO[4][96];
  __shared__ float rbuf[96];

  const int bid = blockIdx.x;
  const int idx = bid >> 3;
  const int n = (bid & 7) * 16 + idx / 21;
  const int bt = idx % 21;
  const int tid = threadIdx.x;
  const int w = tid >> 6, lane = tid & 63, quad = lane >> 4, l16 = lane & 15;

  bf16x8 bf[6][2];
#pragma unroll
  for (int i = 0; i < 6; ++i) {
    bf[i][0] = *(const bf16x8*)(W3fr + ((((bt * 6 + i) * 2 + 0) * 16 + l16) * 4 + quad) * 8);
    bf[i][1] = *(const bf16x8*)(W3fr + ((((bt * 6 + i) * 2 + 1) * 16 + l16) * 4 + quad) * 8);
  }

  const int cntn = cnt[n];
  const int nch = (cntn + 15) >> 4;                 // 16-row chunks (~14..19)
  // lane base pointers; chunk c adds c*1024 (H, bf16) / c*512 (Xt, f32)
  const __bf16* Hb = Hc + ((size_t)n << 9) * 64 + (size_t)l16 * 64 + quad * 8;
  const float*  Xb = Xt + ((size_t)n * 32) * 512 + l16 * 16 + quad * 4;

  floatx2 s2[3] = {{0.f, 0.f}, {0.f, 0.f}, {0.f, 0.f}};
  float o[6] = {0, 0, 0, 0, 0, 0};

  int c = w;                                        // nch >= 13 > 4, always valid
  bf16x8 a0 = *(const bf16x8*)(Hb + (size_t)c * 1024);
  bf16x8 a1 = *(const bf16x8*)(Hb + (size_t)c * 1024 + 32);
  float4 xl4 = *(const float4*)(Xb + c * 512);
  float4 xh4 = *(const float4*)(Xb + c * 512 + 256);

#pragma unroll 1
  while (c < nch) {
    const int cn = c + 4;
    bf16x8 na0, na1;
    float4 nxl, nxh;
    if (cn < nch) {                                 // wave-uniform prefetch
      na0 = *(const bf16x8*)(Hb + (size_t)cn * 1024);
      na1 = *(const bf16x8*)(Hb + (size_t)cn * 1024 + 32);
      nxl = *(const float4*)(Xb + cn * 512);
      nxh = *(const float4*)(Xb + cn * 512 + 256);
    }

#pragma unroll
    for (int t = 0; t < 3; ++t) {
      floatx4 accE = {0.f, 0.f, 0.f, 0.f};
      floatx4 accO = {0.f, 0.f, 0.f, 0.f};
      accE = mfma16(a0, bf[2 * t][0], accE);
      accE = mfma16(a1, bf[2 * t][1], accE);        // logit*log2e incl. b3
      accO = mfma16(a0, bf[2 * t + 1][0], accO);
      accO = mfma16(a1, bf[2 * t + 1][1], accO);
#pragma unroll
      for (int r = 0; r < 4; ++r) {
        floatx2 e2;
        e2.x = __builtin_amdgcn_exp2f(accE[r]);
        e2.y = __builtin_amdgcn_exp2f(accO[r]);
        s2[t] += e2;                                // pad rows add exactly 1.0
        o[2 * t]     = fmaf(e2.x, xl4[r], o[2 * t]);     // x==0 on pad rows
        o[2 * t + 1] = fmaf(e2.y, xh4[r], o[2 * t + 1]);
      }
    }

    c = cn;
    a0 = na0; a1 = na1; xl4 = nxl; xh4 = nxh;       // garbage on exit iter: unused
  }

  // reduce the 4 quads (row groups) within each wave
#pragma unroll
  for (int t = 0; t < 3; ++t) {
    s2[t].x += __shfl_xor(s2[t].x, 16); s2[t].x += __shfl_xor(s2[t].x, 32);
    s2[t].y += __shfl_xor(s2[t].y, 16); s2[t].y += __shfl_xor(s2[t].y, 32);
  }
#pragma unroll
  for (int i = 0; i < 6; ++i) {
    o[i] += __shfl_xor(o[i], 16);
    o[i] += __shfl_xor(o[i], 32);
  }
  if (quad == 0) {
#pragma unroll
    for (int t = 0; t < 3; ++t) {
      redS[w][(2 * t) * 16 + l16]     = s2[t].x;
      redS[w][(2 * t + 1) * 16 + l16] = s2[t].y;
    }
#pragma unroll
    for (int i = 0; i < 6; ++i) redO[w][i * 16 + l16] = o[i];
  }
  __syncthreads();
  if (tid < 96) {
    const float pad = (float)(nch * 16 - cntn);     // exact pad contribution to S
    const float S = redS[0][tid] + redS[1][tid] + redS[2][tid] + redS[3][tid] - pad;
    const float O = redO[0][tid] + redO[1][tid] + redO[2][tid] + redO[3][tid];
    rbuf[tid] = O / S;
  }
  __syncthreads();
  if (tid < 3) {
    float acc = 0.f;
#pragma unroll
    for (int dd = 0; dd < 32; ++dd) acc += rbuf[tid * 32 + dd];
    const int k = bt * 3 + tid;
    out[n * K_ + k] = fmaxf(acc + Tb[k], 0.f);
  }
}

extern "C" void kernel_launch(void* const* d_in, const int* in_sizes, int n_in,
                              void* d_out, int out_size, void* d_ws, size_t ws_size,
                              hipStream_t stream) {
  const float* X  = (const float*)d_in[0];
  const float* Mk = (const float*)d_in[1];
  const float* W1 = (const float*)d_in[2];
  const float* b1 = (const float*)d_in[3];
  const float* W2 = (const float*)d_in[4];
  const float* b2 = (const float*)d_in[5];
  const float* W3 = (const float*)d_in[6];
  const float* b3 = (const float*)d_in[7];
  const float* Tb = (const float*)d_in[8];
  float* out = (float*)d_out;

  char* ws = (char*)d_ws;
  __bf16* Hc    = (__bf16*)(ws + HC_OFF);
  float*  Xt    = (float*)(ws + XT_OFF);
  __bf16* W3fr  = (__bf16*)(ws + W3FR_OFF);
  __bf16* W1fr  = (__bf16*)(ws + W1FR_OFF);
  __bf16* W2fr  = (__bf16*)(ws + W2FR_OFF);
  float*  b1pad = (float*)(ws + B1_OFF);
  int*    pos   = (int*)(ws + POS_OFF);
  int*    cnt   = (int*)(ws + CNT_OFF);

  kern_prep<<<N_, 256, 0, stream>>>(Mk, W1, b1, W2, b2, W3, b3,
                                    W3fr, W1fr, W2fr, b1pad, pos, cnt, Hc, Xt);
  kern_mlp<<<N_ * LX_ / 64, 256, 0, stream>>>(X, W1fr, W2fr, b1pad, pos, Hc, Xt);
  kern_att<<<N_ * 21, 256, 0, stream>>>(Hc, Xt, W3fr, cnt, Tb, out);
}